// Round 1
// baseline (321.683 us; speedup 1.0000x reference)
//
#include <hip/hip_runtime.h>

#define DIMN 1024
#define TN 4096
#define BN 8
#define CBN 4096
#define CDN 8
#define BTN (BN*TN)
#define OUT_ELEMS (BN*DIMN*TN)

typedef float fx4 __attribute__((ext_vector_type(4)));

// ws layout (float offsets)
#define WS_WINT 0          // W_in^T scaled: [d][8], 8192 floats
#define WS_WOUT 8192       // W_out scaled: [o][8], 8192 floats
#define WS_CN   16384      // normalized codebook [j][8], 32768 floats (contiguous with WS_C2)
#define WS_C2   49152      // h = -0.5*sum(c_n^2) per code, 4096 floats
#define WS_LOSS 86016      // 8 floats (per-batch loss accum)
#define WS_CNT  86024      // completion counter (uint bits)
#define WS_ZEP  360448     // z_e partials [8][BTN][8], 2097152 floats

// fused-kernel LDS float offsets (160 KB total)
#define LCB_F   0          // normalized codebook [4096][8]
#define LH_F    32768      // h [4096]
#define LZE_F   36864      // raw z_e [128][8]
#define LEN_F   37888      // e_n [128][8]
#define LCAND_F 38912      // candidates [8 chunks][128 t][2]
// overlays into dead codebook region (after search):
#define LWO_F   0          // W_out [1024][8]
#define LZQ_F   8192       // z_q [8][128]
#define LBO_F   9216       // b_out [1024]

__device__ __forceinline__ float dot4(float4 a, float4 b) {
    float d = a.x * b.x;
    d = fmaf(a.y, b.y, d);
    d = fmaf(a.z, b.z, d);
    d = fmaf(a.w, b.w, d);
    return d;
}
__device__ __forceinline__ void add4(float4& a, float4 b) {
    a.x += b.x; a.y += b.y; a.z += b.z; a.w += b.w;
}

// ---------------- K0: prep weights / codebook / zero loss+counter ----------------
__global__ __launch_bounds__(256) void k0_prep(
    const float* __restrict__ v_in, const float* __restrict__ g_in,
    const float* __restrict__ codebook, const float* __restrict__ v_out,
    const float* __restrict__ g_out, float* __restrict__ ws) {
    __shared__ float sred[5];
    int blk = blockIdx.x, tid = threadIdx.x;
    if (blk < 8) {
        int o = blk;
        const float* v = v_in + o * DIMN;
        float4 x = *(const float4*)(v + tid * 4);
        float p = x.x * x.x + x.y * x.y + x.z * x.z + x.w * x.w;
        for (int off = 32; off >= 1; off >>= 1) p += __shfl_down(p, off, 64);
        if ((tid & 63) == 0) sred[tid >> 6] = p;
        __syncthreads();
        if (tid == 0) {
            float tot = sred[0] + sred[1] + sred[2] + sred[3];
            sred[4] = g_in[o] / sqrtf(tot);
        }
        __syncthreads();
        float s = sred[4];
        ws[WS_WINT + (tid * 4 + 0) * 8 + o] = x.x * s;
        ws[WS_WINT + (tid * 4 + 1) * 8 + o] = x.y * s;
        ws[WS_WINT + (tid * 4 + 2) * 8 + o] = x.z * s;
        ws[WS_WINT + (tid * 4 + 3) * 8 + o] = x.w * s;
    } else if (blk < 12) {
        int r = (blk - 8) * 256 + tid;
        const float* v = v_out + r * 8;
        float4 a = *(const float4*)v;
        float4 b = *(const float4*)(v + 4);
        float n2 = dot4(a, a) + dot4(b, b);
        float s = g_out[r] / sqrtf(n2);
        *(float4*)(ws + WS_WOUT + r * 8)     = make_float4(a.x*s, a.y*s, a.z*s, a.w*s);
        *(float4*)(ws + WS_WOUT + r * 8 + 4) = make_float4(b.x*s, b.y*s, b.z*s, b.w*s);
    } else if (blk < 28) {
        int j = (blk - 12) * 256 + tid;
        const float* c = codebook + j * 8;
        float4 a = *(const float4*)c;
        float4 b = *(const float4*)(c + 4);
        float n2 = dot4(a, a) + dot4(b, b);
        float inv = 1.0f / fmaxf(sqrtf(n2), 1e-12f);
        float4 na = make_float4(a.x*inv, a.y*inv, a.z*inv, a.w*inv);
        float4 nb = make_float4(b.x*inv, b.y*inv, b.z*inv, b.w*inv);
        *(float4*)(ws + WS_CN + j * 8)     = na;
        *(float4*)(ws + WS_CN + j * 8 + 4) = nb;
        ws[WS_C2 + j] = -0.5f * (dot4(na, na) + dot4(nb, nb));  // argmin dist == argmax dot+h
    } else {
        if (tid < 9) ws[WS_LOSS + tid] = 0.0f;   // 8 loss slots + counter
    }
}

// ---------------- K1a: z_e partials -> WS_ZEP[p][t][8], p = half*4+wave ----------------
// (unchanged — proven; partial p covers d in [p*128, p*128+128) ascending)
__global__ __launch_bounds__(256) void k1a_ze(
    const float* __restrict__ z, float* __restrict__ ws) {
    __shared__ float wlds[512 * 8];   // 16 KB: W_in^T rows for this half
    int tid = threadIdx.x, blk = blockIdx.x;
    int b = blk >> 5;
    int r = blk & 31;
    int t0 = (r >> 1) * 256;
    int dbase = (r & 1) * 512;
    #pragma unroll
    for (int i = 0; i < 4; i++) {
        int f4 = tid + i * 256;
        *(float4*)(wlds + f4 * 4) = *(const float4*)(ws + WS_WINT + dbase * 8 + f4 * 4);
    }
    __syncthreads();
    int w = tid >> 6, lane = tid & 63;
    const float* zp = z + ((size_t)(b * DIMN + dbase + w * 128)) * TN + t0 + lane * 4;
    float4 acc[8];
    #pragma unroll
    for (int c = 0; c < 8; c++) acc[c] = make_float4(0.f, 0.f, 0.f, 0.f);
    #pragma unroll 8
    for (int dd = 0; dd < 128; ++dd) {
        fx4 zr = __builtin_nontemporal_load((const fx4*)(zp + (size_t)dd * TN));
        const float* wv = wlds + (w * 128 + dd) * 8;   // wave-uniform -> broadcast
        #pragma unroll
        for (int c = 0; c < 8; c++) {
            float wc = wv[c];
            acc[c].x = fmaf(wc, zr.x, acc[c].x);
            acc[c].y = fmaf(wc, zr.y, acc[c].y);
            acc[c].z = fmaf(wc, zr.z, acc[c].z);
            acc[c].w = fmaf(wc, zr.w, acc[c].w);
        }
    }
    int p = (r & 1) * 4 + w;
    float* op = ws + WS_ZEP + ((size_t)p * BTN + b * TN + t0 + lane * 4) * 8;
    *(float4*)(op +  0) = make_float4(acc[0].x, acc[1].x, acc[2].x, acc[3].x);
    *(float4*)(op +  4) = make_float4(acc[4].x, acc[5].x, acc[6].x, acc[7].x);
    *(float4*)(op +  8) = make_float4(acc[0].y, acc[1].y, acc[2].y, acc[3].y);
    *(float4*)(op + 12) = make_float4(acc[4].y, acc[5].y, acc[6].y, acc[7].y);
    *(float4*)(op + 16) = make_float4(acc[0].z, acc[1].z, acc[2].z, acc[3].z);
    *(float4*)(op + 20) = make_float4(acc[4].z, acc[5].z, acc[6].z, acc[7].z);
    *(float4*)(op + 24) = make_float4(acc[0].w, acc[1].w, acc[2].w, acc[3].w);
    *(float4*)(op + 28) = make_float4(acc[4].w, acc[5].w, acc[6].w, acc[7].w);
}

// ---------------- K_fused: per (b, 128-t tile): assemble z_e, search 4096 codes,
//                  merge, losses, idx out, out-projection. grid 256 x 256 thr ----------------
__global__ __launch_bounds__(256, 1) void k_fused(
    const float* __restrict__ b_in, const float* __restrict__ codebook,
    const float* __restrict__ b_out, float* __restrict__ dout,
    float* __restrict__ ws) {
    __shared__ float sp[40960];   // 160 KB
    int tid = threadIdx.x, blk = blockIdx.x;
    int b = blk >> 5;
    int t0 = (blk & 31) * 128;

    // --- stage normalized codebook + h (contiguous 36864 floats in ws) ---
    #pragma unroll 4
    for (int i = 0; i < 36; i++) {
        int f4 = i * 256 + tid;
        *(float4*)(sp + f4 * 4) = *(const float4*)(ws + WS_CN + f4 * 4);
    }
    // --- assemble z_e once per t (threads 0..127), bitwise-identical fold ---
    if (tid < 128) {
        int bt = b * TN + t0 + tid;
        float4 za = *(const float4*)(b_in);
        float4 zb = *(const float4*)(b_in + 4);
        #pragma unroll
        for (int p = 0; p < 8; p++) {
            const float* pp = ws + WS_ZEP + ((size_t)p * BTN + bt) * 8;
            add4(za, *(const float4*)(pp));
            add4(zb, *(const float4*)(pp + 4));
        }
        *(float4*)(sp + LZE_F + tid * 8)     = za;
        *(float4*)(sp + LZE_F + tid * 8 + 4) = zb;
        float inv = 1.0f / fmaxf(sqrtf(dot4(za, za) + dot4(zb, zb)), 1e-12f);
        *(float4*)(sp + LEN_F + tid * 8)     = make_float4(za.x*inv, za.y*inv, za.z*inv, za.w*inv);
        *(float4*)(sp + LEN_F + tid * 8 + 4) = make_float4(zb.x*inv, zb.y*inv, zb.z*inv, zb.w*inv);
    }
    __syncthreads();

    // --- search: 8 chunks x 32 t-quads; LDS reads are 2-address broadcast ---
    int chunk = tid >> 5, tq = tid & 31;
    float e[4][8];
    #pragma unroll
    for (int tt = 0; tt < 4; tt++) {
        float4 a = *(const float4*)(sp + LEN_F + (tq * 4 + tt) * 8);
        float4 c = *(const float4*)(sp + LEN_F + (tq * 4 + tt) * 8 + 4);
        e[tt][0] = a.x; e[tt][1] = a.y; e[tt][2] = a.z; e[tt][3] = a.w;
        e[tt][4] = c.x; e[tt][5] = c.y; e[tt][6] = c.z; e[tt][7] = c.w;
    }
    float bs[4]; int bi[4];
    #pragma unroll
    for (int tt = 0; tt < 4; tt++) { bs[tt] = -3.4e38f; bi[tt] = 0; }
    const float* cb = sp + chunk * 512 * 8;
    const float* hp = sp + LH_F + chunk * 512;
    #pragma unroll 4
    for (int j = 0; j < 512; ++j) {
        float4 ca = *(const float4*)(cb + j * 8);
        float4 cc = *(const float4*)(cb + j * 8 + 4);
        float hh = hp[j];
        #pragma unroll
        for (int tt = 0; tt < 4; tt++) {
            float s = fmaf(e[tt][0], ca.x, hh);
            s = fmaf(e[tt][1], ca.y, s); s = fmaf(e[tt][2], ca.z, s); s = fmaf(e[tt][3], ca.w, s);
            s = fmaf(e[tt][4], cc.x, s); s = fmaf(e[tt][5], cc.y, s);
            s = fmaf(e[tt][6], cc.z, s); s = fmaf(e[tt][7], cc.w, s);
            if (s > bs[tt]) { bs[tt] = s; bi[tt] = j; }   // strict >: first max == first-min dist
        }
    }
    #pragma unroll
    for (int tt = 0; tt < 4; tt++) {
        *(float2*)(sp + LCAND_F + (chunk * 128 + tq * 4 + tt) * 2) =
            make_float2(bs[tt], __int_as_float(chunk * 512 + bi[tt]));
    }
    __syncthreads();   // search done; codebook LDS region now dead

    if (tid < 128) {
        // --- merge 8 chunk candidates (ascending, strict > keeps lowest index) ---
        float2 c0 = *(const float2*)(sp + LCAND_F + tid * 2);
        float best = c0.x; int idx = __float_as_int(c0.y);
        #pragma unroll
        for (int ch = 1; ch < 8; ch++) {
            float2 cc = *(const float2*)(sp + LCAND_F + (ch * 128 + tid) * 2);
            if (cc.x > best) { best = cc.x; idx = __float_as_int(cc.y); }
        }
        dout[(size_t)OUT_ELEMS + b * TN + t0 + tid] = (float)idx;
        // --- z_q gather (raw codebook) + transpose into LDS + loss ---
        const float* cq = codebook + (size_t)idx * 8;
        float4 qa = *(const float4*)cq, qb = *(const float4*)(cq + 4);
        sp[LZQ_F + 0*128 + tid] = qa.x; sp[LZQ_F + 1*128 + tid] = qa.y;
        sp[LZQ_F + 2*128 + tid] = qa.z; sp[LZQ_F + 3*128 + tid] = qa.w;
        sp[LZQ_F + 4*128 + tid] = qb.x; sp[LZQ_F + 5*128 + tid] = qb.y;
        sp[LZQ_F + 6*128 + tid] = qb.z; sp[LZQ_F + 7*128 + tid] = qb.w;
        float4 za = *(const float4*)(sp + LZE_F + tid * 8);
        float4 zb = *(const float4*)(sp + LZE_F + tid * 8 + 4);
        float4 da = make_float4(za.x-qa.x, za.y-qa.y, za.z-qa.z, za.w-qa.w);
        float4 db = make_float4(zb.x-qb.x, zb.y-qb.y, zb.z-qb.z, zb.w-qb.w);
        float l = dot4(da, da) + dot4(db, db);
        for (int off = 32; off >= 1; off >>= 1) l += __shfl_down(l, off, 64);
        if ((tid & 63) == 0) atomicAdd(ws + WS_LOSS + b, l);
    } else {
        // --- waves 2,3: stage W_out + b_out into dead codebook region ---
        int k = tid - 128;
        #pragma unroll 4
        for (int i = 0; i < 16; i++) {
            int f4 = i * 128 + k;
            *(float4*)(sp + LWO_F + f4 * 4) = *(const float4*)(ws + WS_WOUT + f4 * 4);
        }
        #pragma unroll
        for (int i = 0; i < 2; i++) {
            int f4 = i * 128 + k;
            *(float4*)(sp + LBO_F + f4 * 4) = *(const float4*)(b_out + f4 * 4);
        }
    }
    __syncthreads();

    // --- out-projection: thread (t4, osub) covers 4 t x 128 o ---
    int t4 = tid & 31, osub = tid >> 5;
    int tqf = t4 * 4;
    float4 zr[8];
    #pragma unroll
    for (int c = 0; c < 8; c++) zr[c] = *(const float4*)(sp + LZQ_F + c * 128 + tqf);
    size_t obase = ((size_t)(b * DIMN)) * TN + (size_t)(t0 + tqf);
    for (int k = 0; k < 128; k++) {
        int o = osub * 128 + k;
        float4 wa = *(const float4*)(sp + LWO_F + o * 8);
        float4 wb = *(const float4*)(sp + LWO_F + o * 8 + 4);
        float bo = sp[LBO_F + o];
        float4 acc = make_float4(bo, bo, bo, bo);
        float wc[8] = {wa.x, wa.y, wa.z, wa.w, wb.x, wb.y, wb.z, wb.w};
        #pragma unroll
        for (int c = 0; c < 8; c++) {
            acc.x = fmaf(wc[c], zr[c].x, acc.x);
            acc.y = fmaf(wc[c], zr[c].y, acc.y);
            acc.z = fmaf(wc[c], zr[c].z, acc.z);
            acc.w = fmaf(wc[c], zr[c].w, acc.w);
        }
        acc.x = fminf(fmaxf(acc.x, -8.f), 8.f);
        acc.y = fminf(fmaxf(acc.y, -8.f), 8.f);
        acc.z = fminf(fmaxf(acc.z, -8.f), 8.f);
        acc.w = fminf(fmaxf(acc.w, -8.f), 8.f);
        fx4 st; st.x = acc.x; st.y = acc.y; st.z = acc.z; st.w = acc.w;
        __builtin_nontemporal_store(st, (fx4*)(dout + obase + (size_t)o * TN));
    }

    // --- last block finalizes losses (device-scope atomics, counter pattern) ---
    if (tid == 0) {
        __threadfence();
        unsigned int old = atomicAdd((unsigned int*)(ws + WS_CNT), 1u);
        if (old == 255u) {
            #pragma unroll
            for (int i = 0; i < 8; i++) {
                float v = atomicAdd(ws + WS_LOSS + i, 0.0f);   // coherent read
                dout[(size_t)OUT_ELEMS + BTN + i] = v * (1.25f / 32768.0f);
            }
        }
    }
}

extern "C" void kernel_launch(void* const* d_in, const int* in_sizes, int n_in,
                              void* d_out, int out_size, void* d_ws, size_t ws_size,
                              hipStream_t stream) {
    (void)in_sizes; (void)n_in; (void)out_size; (void)ws_size;
    const float* z        = (const float*)d_in[0];
    const float* v_in     = (const float*)d_in[1];
    const float* g_in     = (const float*)d_in[2];
    const float* b_in     = (const float*)d_in[3];
    const float* codebook = (const float*)d_in[4];
    const float* v_out    = (const float*)d_in[5];
    const float* g_out    = (const float*)d_in[6];
    const float* b_out    = (const float*)d_in[7];
    float* out            = (float*)d_out;
    float* ws             = (float*)d_ws;

    hipLaunchKernelGGL(k0_prep, dim3(29), dim3(256), 0, stream,
                       v_in, g_in, codebook, v_out, g_out, ws);
    hipLaunchKernelGGL(k1a_ze, dim3(256), dim3(256), 0, stream, z, ws);
    hipLaunchKernelGGL(k_fused, dim3(256), dim3(256), 0, stream,
                       b_in, codebook, b_out, out, ws);
}

// Round 2
// 306.134 us; speedup vs baseline: 1.0508x; 1.0508x over previous
//
#include <hip/hip_runtime.h>

#define DIMN 1024
#define TN 4096
#define BN 8
#define CBN 4096
#define CDN 8
#define BTN (BN*TN)
#define OUT_ELEMS (BN*DIMN*TN)

typedef float fx4 __attribute__((ext_vector_type(4)));

// ws layout (float offsets)
#define WS_WINT 0          // W_in^T scaled: [d][8], 8192 floats
#define WS_WOUT 8192       // W_out scaled: [o][8], 8192 floats
#define WS_CN   16384      // normalized codebook [j][8], 32768 floats
#define WS_C2   49152      // h = -0.5*sum(c_n^2) per code, 4096 floats
#define WS_LOSS 86016      // 8 floats (per-batch loss accum)
#define WS_CNT  86024      // completion counter (uint bits)
#define WS_ZEP  360448     // z_e partials [8][BTN][8], 2097152 floats

// ---- k_so LDS float offsets (total 11856 floats = 46.3 KB -> 2-3 blocks/CU) ----
// Region A [0,9296): union of
//   search phase: LCB=0 (1024 codes x 8), LH=8192 (1024 h)
//   out phase:    LWO=0 (skewed W_out, 8256), LBO=8256 (skewed b_out, 1040)
#define LH_F    8192
#define LBO_F   8256
#define LZE_F   9296       // z_e [64][8]
#define LEN_F   9808       // e_n [64][8]
#define LCAND_F 10320      // candidates [8 q][64 t][2]
#define LZQ_F   11344      // z_q transposed [8][64]
#define LDS_TOT 11856

__device__ __forceinline__ float dot4(float4 a, float4 b) {
    float d = a.x * b.x;
    d = fmaf(a.y, b.y, d);
    d = fmaf(a.z, b.z, d);
    d = fmaf(a.w, b.w, d);
    return d;
}
__device__ __forceinline__ void add4(float4& a, float4 b) {
    a.x += b.x; a.y += b.y; a.z += b.z; a.w += b.w;
}

// ---------------- K0: prep weights / codebook / zero loss+counter ----------------
__global__ __launch_bounds__(256) void k0_prep(
    const float* __restrict__ v_in, const float* __restrict__ g_in,
    const float* __restrict__ codebook, const float* __restrict__ v_out,
    const float* __restrict__ g_out, float* __restrict__ ws) {
    __shared__ float sred[5];
    int blk = blockIdx.x, tid = threadIdx.x;
    if (blk < 8) {
        int o = blk;
        const float* v = v_in + o * DIMN;
        float4 x = *(const float4*)(v + tid * 4);
        float p = x.x * x.x + x.y * x.y + x.z * x.z + x.w * x.w;
        for (int off = 32; off >= 1; off >>= 1) p += __shfl_down(p, off, 64);
        if ((tid & 63) == 0) sred[tid >> 6] = p;
        __syncthreads();
        if (tid == 0) {
            float tot = sred[0] + sred[1] + sred[2] + sred[3];
            sred[4] = g_in[o] / sqrtf(tot);
        }
        __syncthreads();
        float s = sred[4];
        ws[WS_WINT + (tid * 4 + 0) * 8 + o] = x.x * s;
        ws[WS_WINT + (tid * 4 + 1) * 8 + o] = x.y * s;
        ws[WS_WINT + (tid * 4 + 2) * 8 + o] = x.z * s;
        ws[WS_WINT + (tid * 4 + 3) * 8 + o] = x.w * s;
    } else if (blk < 12) {
        int r = (blk - 8) * 256 + tid;
        const float* v = v_out + r * 8;
        float4 a = *(const float4*)v;
        float4 b = *(const float4*)(v + 4);
        float n2 = dot4(a, a) + dot4(b, b);
        float s = g_out[r] / sqrtf(n2);
        *(float4*)(ws + WS_WOUT + r * 8)     = make_float4(a.x*s, a.y*s, a.z*s, a.w*s);
        *(float4*)(ws + WS_WOUT + r * 8 + 4) = make_float4(b.x*s, b.y*s, b.z*s, b.w*s);
    } else if (blk < 28) {
        int j = (blk - 12) * 256 + tid;
        const float* c = codebook + j * 8;
        float4 a = *(const float4*)c;
        float4 b = *(const float4*)(c + 4);
        float n2 = dot4(a, a) + dot4(b, b);
        float inv = 1.0f / fmaxf(sqrtf(n2), 1e-12f);
        float4 na = make_float4(a.x*inv, a.y*inv, a.z*inv, a.w*inv);
        float4 nb = make_float4(b.x*inv, b.y*inv, b.z*inv, b.w*inv);
        *(float4*)(ws + WS_CN + j * 8)     = na;
        *(float4*)(ws + WS_CN + j * 8 + 4) = nb;
        ws[WS_C2 + j] = -0.5f * (dot4(na, na) + dot4(nb, nb));  // argmin dist == argmax dot+h
    } else {
        if (tid < 9) ws[WS_LOSS + tid] = 0.0f;   // 8 loss slots + counter
    }
}

// ---------------- K1a: z_e partials -> WS_ZEP[p][t][8] (unchanged, proven) ----------------
__global__ __launch_bounds__(256) void k1a_ze(
    const float* __restrict__ z, float* __restrict__ ws) {
    __shared__ float wlds[512 * 8];   // 16 KB: W_in^T rows for this half
    int tid = threadIdx.x, blk = blockIdx.x;
    int b = blk >> 5;
    int r = blk & 31;
    int t0 = (r >> 1) * 256;
    int dbase = (r & 1) * 512;
    #pragma unroll
    for (int i = 0; i < 4; i++) {
        int f4 = tid + i * 256;
        *(float4*)(wlds + f4 * 4) = *(const float4*)(ws + WS_WINT + dbase * 8 + f4 * 4);
    }
    __syncthreads();
    int w = tid >> 6, lane = tid & 63;
    const float* zp = z + ((size_t)(b * DIMN + dbase + w * 128)) * TN + t0 + lane * 4;
    float4 acc[8];
    #pragma unroll
    for (int c = 0; c < 8; c++) acc[c] = make_float4(0.f, 0.f, 0.f, 0.f);
    #pragma unroll 8
    for (int dd = 0; dd < 128; ++dd) {
        fx4 zr = __builtin_nontemporal_load((const fx4*)(zp + (size_t)dd * TN));
        const float* wv = wlds + (w * 128 + dd) * 8;   // wave-uniform -> broadcast
        #pragma unroll
        for (int c = 0; c < 8; c++) {
            float wc = wv[c];
            acc[c].x = fmaf(wc, zr.x, acc[c].x);
            acc[c].y = fmaf(wc, zr.y, acc[c].y);
            acc[c].z = fmaf(wc, zr.z, acc[c].z);
            acc[c].w = fmaf(wc, zr.w, acc[c].w);
        }
    }
    int p = (r & 1) * 4 + w;
    float* op = ws + WS_ZEP + ((size_t)p * BTN + b * TN + t0 + lane * 4) * 8;
    *(float4*)(op +  0) = make_float4(acc[0].x, acc[1].x, acc[2].x, acc[3].x);
    *(float4*)(op +  4) = make_float4(acc[4].x, acc[5].x, acc[6].x, acc[7].x);
    *(float4*)(op +  8) = make_float4(acc[0].y, acc[1].y, acc[2].y, acc[3].y);
    *(float4*)(op + 12) = make_float4(acc[4].y, acc[5].y, acc[6].y, acc[7].y);
    *(float4*)(op + 16) = make_float4(acc[0].z, acc[1].z, acc[2].z, acc[3].z);
    *(float4*)(op + 20) = make_float4(acc[4].z, acc[5].z, acc[6].z, acc[7].z);
    *(float4*)(op + 24) = make_float4(acc[0].w, acc[1].w, acc[2].w, acc[3].w);
    *(float4*)(op + 28) = make_float4(acc[4].w, acc[5].w, acc[6].w, acc[7].w);
}

// ---------------- K_so: fused search + merge + loss + idx + out-projection ----------------
// grid 512 = (b = blk>>6, 64-t tile = blk&63). 256 threads, ~46 KB LDS -> 2 blocks/CU.
// Codebook scanned in 4 staged chunks of 1024 codes (36 KB LDS, k1b's proven pattern).
__global__ __launch_bounds__(256, 2) void k_so(
    const float* __restrict__ b_in, const float* __restrict__ codebook,
    const float* __restrict__ b_out, float* __restrict__ dout,
    float* __restrict__ ws) {
    __shared__ float sp[LDS_TOT];
    int tid = threadIdx.x, blk = blockIdx.x;
    int b = blk >> 6;
    int t0 = (blk & 63) * 64;

    // --- phase 0: assemble z_e/e_n (wave 0)  ||  stage codebook chunk 0 (waves 1-3) ---
    if (tid < 64) {
        int bt = b * TN + t0 + tid;
        float4 za = *(const float4*)(b_in);
        float4 zb = *(const float4*)(b_in + 4);
        #pragma unroll
        for (int p = 0; p < 8; p++) {             // ascending p: bitwise-identical fold
            const float* pp = ws + WS_ZEP + ((size_t)p * BTN + bt) * 8;
            add4(za, *(const float4*)(pp));
            add4(zb, *(const float4*)(pp + 4));
        }
        *(float4*)(sp + LZE_F + tid * 8)     = za;
        *(float4*)(sp + LZE_F + tid * 8 + 4) = zb;
        float inv = 1.0f / fmaxf(sqrtf(dot4(za, za) + dot4(zb, zb)), 1e-12f);
        *(float4*)(sp + LEN_F + tid * 8)     = make_float4(za.x*inv, za.y*inv, za.z*inv, za.w*inv);
        *(float4*)(sp + LEN_F + tid * 8 + 4) = make_float4(zb.x*inv, zb.y*inv, zb.z*inv, zb.w*inv);
    } else {
        int i = tid - 64;
        #pragma unroll
        for (int r = 0; r < 12; r++) {            // 12*192 = 2304 float4 = 1024 rows + 256 h-quads
            int f4 = r * 192 + i;
            if (f4 < 2048) {
                *(float4*)(sp + f4 * 4) = *(const float4*)(ws + WS_CN + f4 * 4);
            } else {
                int g = f4 - 2048;
                *(float4*)(sp + LH_F + g * 4) = *(const float4*)(ws + WS_C2 + g * 4);
            }
        }
    }
    __syncthreads();

    // --- load e_n fragments: thread = (t-pair t2, eighth q) ---
    int t2 = tid & 31, q = tid >> 5;
    int ta = t2 * 2, tb = ta + 1;
    float ea[8], eb[8];
    {
        float4 a0 = *(const float4*)(sp + LEN_F + ta * 8);
        float4 a1 = *(const float4*)(sp + LEN_F + ta * 8 + 4);
        float4 b0 = *(const float4*)(sp + LEN_F + tb * 8);
        float4 b1 = *(const float4*)(sp + LEN_F + tb * 8 + 4);
        ea[0]=a0.x; ea[1]=a0.y; ea[2]=a0.z; ea[3]=a0.w;
        ea[4]=a1.x; ea[5]=a1.y; ea[6]=a1.z; ea[7]=a1.w;
        eb[0]=b0.x; eb[1]=b0.y; eb[2]=b0.z; eb[3]=b0.w;
        eb[4]=b1.x; eb[5]=b1.y; eb[6]=b1.z; eb[7]=b1.w;
    }

    float bs0 = -3.4e38f, bs1 = -3.4e38f;
    int bj0 = 0, bj1 = 0;
    const float* cbp = sp + q * 128 * 8;          // this thread's 128-code slice of the chunk
    const float* hp  = sp + LH_F + q * 128;

    for (int c = 0; c < 4; c++) {
        if (c > 0) {   // restage chunk c (buffer free: post-scan sync below)
            #pragma unroll
            for (int r = 0; r < 9; r++) {         // 9*256 = 2304 float4
                int f4 = r * 256 + tid;
                if (f4 < 2048) {
                    *(float4*)(sp + f4 * 4) = *(const float4*)(ws + WS_CN + (size_t)c * 8192 + f4 * 4);
                } else {
                    int g = f4 - 2048;
                    *(float4*)(sp + LH_F + g * 4) = *(const float4*)(ws + WS_C2 + c * 1024 + g * 4);
                }
            }
            __syncthreads();
        }
        int jg = c * 1024 + q * 128;              // ascending global j within slice
        #pragma unroll 4
        for (int j = 0; j < 128; ++j) {
            float4 ca = *(const float4*)(cbp + j * 8);
            float4 cc = *(const float4*)(cbp + j * 8 + 4);
            float hh = hp[j];
            float s0 = fmaf(ea[0], ca.x, hh);     // same chain as proven k1b
            s0 = fmaf(ea[1], ca.y, s0); s0 = fmaf(ea[2], ca.z, s0); s0 = fmaf(ea[3], ca.w, s0);
            s0 = fmaf(ea[4], cc.x, s0); s0 = fmaf(ea[5], cc.y, s0);
            s0 = fmaf(ea[6], cc.z, s0); s0 = fmaf(ea[7], cc.w, s0);
            float s1 = fmaf(eb[0], ca.x, hh);
            s1 = fmaf(eb[1], ca.y, s1); s1 = fmaf(eb[2], ca.z, s1); s1 = fmaf(eb[3], ca.w, s1);
            s1 = fmaf(eb[4], cc.x, s1); s1 = fmaf(eb[5], cc.y, s1);
            s1 = fmaf(eb[6], cc.z, s1); s1 = fmaf(eb[7], cc.w, s1);
            if (s0 > bs0) { bs0 = s0; bj0 = jg + j; }   // strict >: first-min within slice
            if (s1 > bs1) { bs1 = s1; bj1 = jg + j; }
        }
        __syncthreads();   // scan done before restage / before cand region reuse
    }

    // --- publish candidates: [q][t][2] ---
    *(float4*)(sp + LCAND_F + (q * 64 + ta) * 2) =
        make_float4(bs0, __int_as_float(bj0), bs1, __int_as_float(bj1));
    __syncthreads();

    // --- merge + gather + loss (wave 0)  ||  stage W_out/b_out into dead cb region ---
    if (tid < 64) {
        int t = tid;
        float2 c0 = *(const float2*)(sp + LCAND_F + t * 2);
        float best = c0.x; int idx = __float_as_int(c0.y);
        #pragma unroll
        for (int q2 = 1; q2 < 8; q2++) {
            float2 cq = *(const float2*)(sp + LCAND_F + (q2 * 64 + t) * 2);
            int j2 = __float_as_int(cq.y);
            if (cq.x > best || (cq.x == best && j2 < idx)) { best = cq.x; idx = j2; }
        }
        dout[(size_t)OUT_ELEMS + b * TN + t0 + t] = (float)idx;
        const float* cq = codebook + (size_t)idx * 8;     // raw (un-normalized)
        float4 qa = *(const float4*)cq, qb = *(const float4*)(cq + 4);
        sp[LZQ_F + 0*64 + t] = qa.x; sp[LZQ_F + 1*64 + t] = qa.y;
        sp[LZQ_F + 2*64 + t] = qa.z; sp[LZQ_F + 3*64 + t] = qa.w;
        sp[LZQ_F + 4*64 + t] = qb.x; sp[LZQ_F + 5*64 + t] = qb.y;
        sp[LZQ_F + 6*64 + t] = qb.z; sp[LZQ_F + 7*64 + t] = qb.w;
        float4 za = *(const float4*)(sp + LZE_F + t * 8);
        float4 zb = *(const float4*)(sp + LZE_F + t * 8 + 4);
        float4 da = make_float4(za.x-qa.x, za.y-qa.y, za.z-qa.z, za.w-qa.w);
        float4 db = make_float4(zb.x-qb.x, zb.y-qb.y, zb.z-qb.z, zb.w-qb.w);
        float l = dot4(da, da) + dot4(db, db);
        for (int off = 32; off >= 1; off >>= 1) l += __shfl_down(l, off, 64);
        if (t == 0) atomicAdd(ws + WS_LOSS + b, l);
    } else {
        int i = tid - 64;
        #pragma unroll
        for (int r = 0; r < 11; r++) {            // W_out: 2048 float4, +4-float skew per 64 rows
            int f4 = r * 192 + i;
            if (f4 < 2048) {
                float4 v = *(const float4*)(ws + WS_WOUT + f4 * 4);
                *(float4*)(sp + f4 * 4 + 4 * (f4 >> 7)) = v;
            }
        }
        #pragma unroll
        for (int r = 0; r < 2; r++) {             // b_out: skewed scalar writes
            int f = r * 192 + i;
            if (f < 256) {
                float4 v = *(const float4*)(b_out + f * 4);
                int sk = f >> 4;
                sp[LBO_F + f * 4 + sk + 0] = v.x;
                sp[LBO_F + f * 4 + sk + 1] = v.y;
                sp[LBO_F + f * 4 + sk + 2] = v.z;
                sp[LBO_F + f * 4 + sk + 3] = v.w;
            }
        }
    }
    __syncthreads();

    // --- out-projection: thread (t-quad t4, o-group og) covers 4 t x 64 o ---
    int t4 = tid & 15, og = tid >> 4;
    float4 zr[8];
    #pragma unroll
    for (int c = 0; c < 8; c++) zr[c] = *(const float4*)(sp + LZQ_F + c * 64 + t4 * 4);
    size_t obase = ((size_t)(b * DIMN + og * 64)) * TN + (size_t)(t0 + t4 * 4);
    for (int k = 0; k < 64; k++) {
        int o = og * 64 + k;
        const float* wrow = sp + o * 8 + 4 * og;  // skewed: conflict-free 4-row wave reads
        float4 wa = *(const float4*)(wrow);
        float4 wb = *(const float4*)(wrow + 4);
        float bo = sp[LBO_F + o + og];
        float4 acc = make_float4(bo, bo, bo, bo);
        float wc[8] = {wa.x, wa.y, wa.z, wa.w, wb.x, wb.y, wb.z, wb.w};
        #pragma unroll
        for (int c = 0; c < 8; c++) {
            acc.x = fmaf(wc[c], zr[c].x, acc.x);
            acc.y = fmaf(wc[c], zr[c].y, acc.y);
            acc.z = fmaf(wc[c], zr[c].z, acc.z);
            acc.w = fmaf(wc[c], zr[c].w, acc.w);
        }
        acc.x = fminf(fmaxf(acc.x, -8.f), 8.f);
        acc.y = fminf(fmaxf(acc.y, -8.f), 8.f);
        acc.z = fminf(fmaxf(acc.z, -8.f), 8.f);
        acc.w = fminf(fmaxf(acc.w, -8.f), 8.f);
        fx4 st; st.x = acc.x; st.y = acc.y; st.z = acc.z; st.w = acc.w;
        __builtin_nontemporal_store(st, (fx4*)(dout + obase + (size_t)k * TN));
    }

    // --- last block finalizes losses (device-scope counter pattern, proven r1) ---
    if (tid == 0) {
        __threadfence();
        unsigned int old = atomicAdd((unsigned int*)(ws + WS_CNT), 1u);
        if (old == 511u) {
            #pragma unroll
            for (int i = 0; i < 8; i++) {
                float v = atomicAdd(ws + WS_LOSS + i, 0.0f);   // coherent read
                dout[(size_t)OUT_ELEMS + BTN + i] = v * (1.25f / 32768.0f);
            }
        }
    }
}

extern "C" void kernel_launch(void* const* d_in, const int* in_sizes, int n_in,
                              void* d_out, int out_size, void* d_ws, size_t ws_size,
                              hipStream_t stream) {
    (void)in_sizes; (void)n_in; (void)out_size; (void)ws_size;
    const float* z        = (const float*)d_in[0];
    const float* v_in     = (const float*)d_in[1];
    const float* g_in     = (const float*)d_in[2];
    const float* b_in     = (const float*)d_in[3];
    const float* codebook = (const float*)d_in[4];
    const float* v_out    = (const float*)d_in[5];
    const float* g_out    = (const float*)d_in[6];
    const float* b_out    = (const float*)d_in[7];
    float* out            = (float*)d_out;
    float* ws             = (float*)d_ws;

    hipLaunchKernelGGL(k0_prep, dim3(29), dim3(256), 0, stream,
                       v_in, g_in, codebook, v_out, g_out, ws);
    hipLaunchKernelGGL(k1a_ze, dim3(256), dim3(256), 0, stream, z, ws);
    hipLaunchKernelGGL(k_so, dim3(512), dim3(256), 0, stream,
                       b_in, codebook, b_out, out, ws);
}

// Round 3
// 294.858 us; speedup vs baseline: 1.0910x; 1.0382x over previous
//
#include <hip/hip_runtime.h>

#define DIMN 1024
#define TN 4096
#define BN 8
#define CBN 4096
#define CDN 8
#define BTN (BN*TN)
#define OUT_ELEMS (BN*DIMN*TN)

typedef float fx4 __attribute__((ext_vector_type(4)));
typedef float fx2 __attribute__((ext_vector_type(2)));

// ws layout (float offsets)
#define WS_WINT 0          // W_in^T scaled: [d][8], 8192 floats
#define WS_WOUT 8192       // W_out scaled: [o][8], 8192 floats
#define WS_CN   16384      // normalized codebook [j][8], 32768 floats
#define WS_C2   49152      // h = -0.5*sum(c_n^2) per code, 4096 floats
#define WS_LOSS 86016      // 8 floats (per-batch loss accum)
#define WS_CNT  86024      // completion counter (uint bits)

// ---- k_mega LDS float offsets (15696 floats = 61.3 KB -> 2 blocks/CU) ----
// Region A [0,9296): phase Z: W_in^T[1024][8] (8192). out phase: W_out skewed
//   (8256) + b_out skewed at LBO_F.
#define LBO_F   8256
#define LZEP_F  9296       // zep partials: [64 t] stride 68, [8 p][8 c] -> 4352
#define LZE_F   13648      // z_e [64][8]
#define LEN_F   14160      // e_n [64][8]
#define LCAND_F 14672      // candidates [4 waves][64 t][2]
#define LZQ_F   15184      // z_q transposed [8][64]
#define LDS_TOT 15696

__device__ __forceinline__ float dot4(float4 a, float4 b) {
    float d = a.x * b.x;
    d = fmaf(a.y, b.y, d);
    d = fmaf(a.z, b.z, d);
    d = fmaf(a.w, b.w, d);
    return d;
}
__device__ __forceinline__ void add4(float4& a, float4 b) {
    a.x += b.x; a.y += b.y; a.z += b.z; a.w += b.w;
}

// ---------------- K0: prep weights / codebook / zero loss+counter ----------------
__global__ __launch_bounds__(256) void k0_prep(
    const float* __restrict__ v_in, const float* __restrict__ g_in,
    const float* __restrict__ codebook, const float* __restrict__ v_out,
    const float* __restrict__ g_out, float* __restrict__ ws) {
    __shared__ float sred[5];
    int blk = blockIdx.x, tid = threadIdx.x;
    if (blk < 8) {
        int o = blk;
        const float* v = v_in + o * DIMN;
        float4 x = *(const float4*)(v + tid * 4);
        float p = x.x * x.x + x.y * x.y + x.z * x.z + x.w * x.w;
        for (int off = 32; off >= 1; off >>= 1) p += __shfl_down(p, off, 64);
        if ((tid & 63) == 0) sred[tid >> 6] = p;
        __syncthreads();
        if (tid == 0) {
            float tot = sred[0] + sred[1] + sred[2] + sred[3];
            sred[4] = g_in[o] / sqrtf(tot);
        }
        __syncthreads();
        float s = sred[4];
        ws[WS_WINT + (tid * 4 + 0) * 8 + o] = x.x * s;
        ws[WS_WINT + (tid * 4 + 1) * 8 + o] = x.y * s;
        ws[WS_WINT + (tid * 4 + 2) * 8 + o] = x.z * s;
        ws[WS_WINT + (tid * 4 + 3) * 8 + o] = x.w * s;
    } else if (blk < 12) {
        int r = (blk - 8) * 256 + tid;
        const float* v = v_out + r * 8;
        float4 a = *(const float4*)v;
        float4 b = *(const float4*)(v + 4);
        float n2 = dot4(a, a) + dot4(b, b);
        float s = g_out[r] / sqrtf(n2);
        *(float4*)(ws + WS_WOUT + r * 8)     = make_float4(a.x*s, a.y*s, a.z*s, a.w*s);
        *(float4*)(ws + WS_WOUT + r * 8 + 4) = make_float4(b.x*s, b.y*s, b.z*s, b.w*s);
    } else if (blk < 28) {
        int j = (blk - 12) * 256 + tid;
        const float* c = codebook + j * 8;
        float4 a = *(const float4*)c;
        float4 b = *(const float4*)(c + 4);
        float n2 = dot4(a, a) + dot4(b, b);
        float inv = 1.0f / fmaxf(sqrtf(n2), 1e-12f);
        float4 na = make_float4(a.x*inv, a.y*inv, a.z*inv, a.w*inv);
        float4 nb = make_float4(b.x*inv, b.y*inv, b.z*inv, b.w*inv);
        *(float4*)(ws + WS_CN + j * 8)     = na;
        *(float4*)(ws + WS_CN + j * 8 + 4) = nb;
        ws[WS_C2 + j] = -0.5f * (dot4(na, na) + dot4(nb, nb));  // argmin dist == argmax dot+h
    } else {
        if (tid < 9) ws[WS_LOSS + tid] = 0.0f;   // 8 loss slots + counter
    }
}

// ---------------- K_mega: z_e + search + merge + loss + idx + out-projection ----------------
// grid 512 = (b = blk>>6, 64-t tile = blk&63), 256 threads, 61.3 KB LDS -> 2 blocks/CU.
// Search is register-blocked: codes stream from L2 (global), e_n lives in VGPRs.
__global__ __launch_bounds__(256, 2) void k_mega(
    const float* __restrict__ z, const float* __restrict__ b_in,
    const float* __restrict__ codebook, const float* __restrict__ b_out,
    float* __restrict__ dout, float* __restrict__ ws) {
    __shared__ float sp[LDS_TOT];
    int tid = threadIdx.x, blk = blockIdx.x;
    int b = blk >> 6;
    int t0 = (blk & 63) * 64;

    // ---- phase Z: stage W_in^T [1024][8] into region A ----
    #pragma unroll
    for (int i = 0; i < 8; i++) {
        int f4 = tid + i * 256;
        *(float4*)(sp + f4 * 4) = *(const float4*)(ws + WS_WINT + f4 * 4);
    }
    __syncthreads();
    {
        // thread = (p-chunk = tid>>5, t-pair = tid&31); replicates k1a's chains exactly:
        // partial p covers d in [p*128, p*128+128), dd ascending, per-(t,c) fma chain.
        int p = tid >> 5, tpair = tid & 31;
        int tA = tpair * 2;
        const float* zp = z + ((size_t)(b * DIMN + p * 128)) * TN + t0 + tA;
        float4 a0a = make_float4(0.f,0.f,0.f,0.f), a0b = make_float4(0.f,0.f,0.f,0.f);
        float4 a1a = make_float4(0.f,0.f,0.f,0.f), a1b = make_float4(0.f,0.f,0.f,0.f);
        #pragma unroll 8
        for (int dd = 0; dd < 128; ++dd) {
            fx2 zv = __builtin_nontemporal_load((const fx2*)(zp + (size_t)dd * TN));
            const float* wv = sp + (p * 128 + dd) * 8;   // 32-lane-uniform -> broadcast
            float4 w0 = *(const float4*)wv;
            float4 w1 = *(const float4*)(wv + 4);
            a0a.x = fmaf(w0.x, zv.x, a0a.x); a0a.y = fmaf(w0.y, zv.x, a0a.y);
            a0a.z = fmaf(w0.z, zv.x, a0a.z); a0a.w = fmaf(w0.w, zv.x, a0a.w);
            a0b.x = fmaf(w1.x, zv.x, a0b.x); a0b.y = fmaf(w1.y, zv.x, a0b.y);
            a0b.z = fmaf(w1.z, zv.x, a0b.z); a0b.w = fmaf(w1.w, zv.x, a0b.w);
            a1a.x = fmaf(w0.x, zv.y, a1a.x); a1a.y = fmaf(w0.y, zv.y, a1a.y);
            a1a.z = fmaf(w0.z, zv.y, a1a.z); a1a.w = fmaf(w0.w, zv.y, a1a.w);
            a1b.x = fmaf(w1.x, zv.y, a1b.x); a1b.y = fmaf(w1.y, zv.y, a1b.y);
            a1b.z = fmaf(w1.z, zv.y, a1b.z); a1b.w = fmaf(w1.w, zv.y, a1b.w);
        }
        float* q0 = sp + LZEP_F + tA * 68 + p * 8;        // +4/t skew: spreads banks
        *(float4*)(q0)     = a0a;
        *(float4*)(q0 + 4) = a0b;
        float* q1 = sp + LZEP_F + (tA + 1) * 68 + p * 8;
        *(float4*)(q1)     = a1a;
        *(float4*)(q1 + 4) = a1b;
    }
    __syncthreads();

    // ---- fold + normalize (tid<64): bitwise-identical to proven k_so fold ----
    if (tid < 64) {
        int t = tid;
        float4 za = *(const float4*)(b_in);
        float4 zb = *(const float4*)(b_in + 4);
        #pragma unroll
        for (int p = 0; p < 8; p++) {                     // ascending p
            const float* pp = sp + LZEP_F + t * 68 + p * 8;
            add4(za, *(const float4*)(pp));
            add4(zb, *(const float4*)(pp + 4));
        }
        *(float4*)(sp + LZE_F + t * 8)     = za;
        *(float4*)(sp + LZE_F + t * 8 + 4) = zb;
        float inv = 1.0f / fmaxf(sqrtf(dot4(za, za) + dot4(zb, zb)), 1e-12f);
        *(float4*)(sp + LEN_F + t * 8)     = make_float4(za.x*inv, za.y*inv, za.z*inv, za.w*inv);
        *(float4*)(sp + LEN_F + t * 8 + 4) = make_float4(zb.x*inv, zb.y*inv, zb.z*inv, zb.w*inv);
    }
    __syncthreads();

    // ---- search: register-blocked, codes from L2, no LDS / no barriers in loop ----
    int co = tid >> 3, tt = tid & 7;   // 32 code-octets x 8 t-groups
    float en[8][8];                    // e_n for my 8 t's (static indexing only)
    #pragma unroll
    for (int k = 0; k < 8; k++) {
        float4 u = *(const float4*)(sp + LEN_F + (tt * 8 + k) * 8);
        float4 v = *(const float4*)(sp + LEN_F + (tt * 8 + k) * 8 + 4);
        en[k][0]=u.x; en[k][1]=u.y; en[k][2]=u.z; en[k][3]=u.w;
        en[k][4]=v.x; en[k][5]=v.y; en[k][6]=v.z; en[k][7]=v.w;
    }
    float bs[8]; int bj[8];
    #pragma unroll
    for (int k = 0; k < 8; k++) { bs[k] = -3.4e38f; bj[k] = 0; }
    #pragma unroll 1
    for (int ci = 0; ci < 16; ++ci) {
        int j0 = ci * 256 + co * 8;    // my 8 codes this chunk, ascending j across ci
        #pragma unroll
        for (int qh = 0; qh < 2; ++qh) {
            int jq = j0 + qh * 4;
            const float* cg = ws + WS_CN + (size_t)jq * 8;   // 128B contiguous / thread
            float4 ca[4], cb[4];
            #pragma unroll
            for (int k = 0; k < 4; k++) {
                ca[k] = *(const float4*)(cg + k * 8);
                cb[k] = *(const float4*)(cg + k * 8 + 4);
            }
            float4 hqv = *(const float4*)(ws + WS_C2 + jq);
            float hv[4] = {hqv.x, hqv.y, hqv.z, hqv.w};
            #pragma unroll
            for (int k = 0; k < 4; k++) {
                #pragma unroll
                for (int t = 0; t < 8; t++) {
                    float s = fmaf(en[t][0], ca[k].x, hv[k]);   // proven chain order
                    s = fmaf(en[t][1], ca[k].y, s); s = fmaf(en[t][2], ca[k].z, s);
                    s = fmaf(en[t][3], ca[k].w, s);
                    s = fmaf(en[t][4], cb[k].x, s); s = fmaf(en[t][5], cb[k].y, s);
                    s = fmaf(en[t][6], cb[k].z, s); s = fmaf(en[t][7], cb[k].w, s);
                    if (s > bs[t]) { bs[t] = s; bj[t] = jq + k; }  // strict >: lowest j in thread
                }
            }
        }
    }
    // ---- in-wave merge across co (lowest-j-among-max is assoc+comm -> butterfly OK) ----
    #pragma unroll
    for (int st = 8; st <= 32; st <<= 1) {
        #pragma unroll
        for (int t = 0; t < 8; t++) {
            float os = __shfl_xor(bs[t], st, 64);
            int   oj = __shfl_xor(bj[t], st, 64);
            if (os > bs[t] || (os == bs[t] && oj < bj[t])) { bs[t] = os; bj[t] = oj; }
        }
    }
    if ((tid & 63) < 8) {              // lane tt of each wave publishes its 8 t's
        int w = tid >> 6;
        #pragma unroll
        for (int k = 0; k < 8; k++)
            *(float2*)(sp + LCAND_F + (w * 64 + tt * 8 + k) * 2) =
                make_float2(bs[k], __int_as_float(bj[k]));
    }
    __syncthreads();

    // ---- merge waves + gather + loss (tid<64)  ||  stage W_out/b_out (tid>=64) ----
    if (tid < 64) {
        int t = tid;
        float2 c0 = *(const float2*)(sp + LCAND_F + t * 2);
        float best = c0.x; int idx = __float_as_int(c0.y);
        #pragma unroll
        for (int w2 = 1; w2 < 4; w2++) {
            float2 cw = *(const float2*)(sp + LCAND_F + (w2 * 64 + t) * 2);
            int j2 = __float_as_int(cw.y);
            if (cw.x > best || (cw.x == best && j2 < idx)) { best = cw.x; idx = j2; }
        }
        dout[(size_t)OUT_ELEMS + b * TN + t0 + t] = (float)idx;
        const float* cq = codebook + (size_t)idx * 8;     // raw (un-normalized)
        float4 qa = *(const float4*)cq, qb = *(const float4*)(cq + 4);
        sp[LZQ_F + 0*64 + t] = qa.x; sp[LZQ_F + 1*64 + t] = qa.y;
        sp[LZQ_F + 2*64 + t] = qa.z; sp[LZQ_F + 3*64 + t] = qa.w;
        sp[LZQ_F + 4*64 + t] = qb.x; sp[LZQ_F + 5*64 + t] = qb.y;
        sp[LZQ_F + 6*64 + t] = qb.z; sp[LZQ_F + 7*64 + t] = qb.w;
        float4 za = *(const float4*)(sp + LZE_F + t * 8);
        float4 zb = *(const float4*)(sp + LZE_F + t * 8 + 4);
        float4 da = make_float4(za.x-qa.x, za.y-qa.y, za.z-qa.z, za.w-qa.w);
        float4 db = make_float4(zb.x-qb.x, zb.y-qb.y, zb.z-qb.z, zb.w-qb.w);
        float l = dot4(da, da) + dot4(db, db);
        for (int off = 32; off >= 1; off >>= 1) l += __shfl_down(l, off, 64);
        if (t == 0) atomicAdd(ws + WS_LOSS + b, l);
    } else {
        int i = tid - 64;
        #pragma unroll
        for (int r = 0; r < 11; r++) {            // W_out: 2048 float4, +4 skew per 128 f4
            int f4 = r * 192 + i;
            if (f4 < 2048) {
                float4 v = *(const float4*)(ws + WS_WOUT + f4 * 4);
                *(float4*)(sp + f4 * 4 + 4 * (f4 >> 7)) = v;
            }
        }
        #pragma unroll
        for (int r = 0; r < 2; r++) {             // b_out: skewed scalar writes
            int f = r * 192 + i;
            if (f < 256) {
                float4 v = *(const float4*)(b_out + f * 4);
                int sk = f >> 4;
                sp[LBO_F + f * 4 + sk + 0] = v.x;
                sp[LBO_F + f * 4 + sk + 1] = v.y;
                sp[LBO_F + f * 4 + sk + 2] = v.z;
                sp[LBO_F + f * 4 + sk + 3] = v.w;
            }
        }
    }
    __syncthreads();

    // ---- out-projection: thread (t-quad t4, o-group og) covers 4 t x 64 o ----
    int t4 = tid & 15, og = tid >> 4;
    float4 zr[8];
    #pragma unroll
    for (int c = 0; c < 8; c++) zr[c] = *(const float4*)(sp + LZQ_F + c * 64 + t4 * 4);
    size_t obase = ((size_t)(b * DIMN + og * 64)) * TN + (size_t)(t0 + t4 * 4);
    for (int k = 0; k < 64; k++) {
        int o = og * 64 + k;
        const float* wrow = sp + o * 8 + 4 * og;  // skewed: conflict-free 4-row wave reads
        float4 wa = *(const float4*)(wrow);
        float4 wb = *(const float4*)(wrow + 4);
        float bo = sp[LBO_F + o + og];
        float4 acc = make_float4(bo, bo, bo, bo);
        float wc[8] = {wa.x, wa.y, wa.z, wa.w, wb.x, wb.y, wb.z, wb.w};
        #pragma unroll
        for (int c = 0; c < 8; c++) {
            acc.x = fmaf(wc[c], zr[c].x, acc.x);
            acc.y = fmaf(wc[c], zr[c].y, acc.y);
            acc.z = fmaf(wc[c], zr[c].z, acc.z);
            acc.w = fmaf(wc[c], zr[c].w, acc.w);
        }
        acc.x = fminf(fmaxf(acc.x, -8.f), 8.f);
        acc.y = fminf(fmaxf(acc.y, -8.f), 8.f);
        acc.z = fminf(fmaxf(acc.z, -8.f), 8.f);
        acc.w = fminf(fmaxf(acc.w, -8.f), 8.f);
        fx4 st; st.x = acc.x; st.y = acc.y; st.z = acc.z; st.w = acc.w;
        __builtin_nontemporal_store(st, (fx4*)(dout + obase + (size_t)k * TN));
    }

    // ---- last block finalizes losses (device-scope counter pattern, proven) ----
    if (tid == 0) {
        __threadfence();
        unsigned int old = atomicAdd((unsigned int*)(ws + WS_CNT), 1u);
        if (old == 511u) {
            #pragma unroll
            for (int i = 0; i < 8; i++) {
                float v = atomicAdd(ws + WS_LOSS + i, 0.0f);   // coherent read
                dout[(size_t)OUT_ELEMS + BTN + i] = v * (1.25f / 32768.0f);
            }
        }
    }
}

extern "C" void kernel_launch(void* const* d_in, const int* in_sizes, int n_in,
                              void* d_out, int out_size, void* d_ws, size_t ws_size,
                              hipStream_t stream) {
    (void)in_sizes; (void)n_in; (void)out_size; (void)ws_size;
    const float* z        = (const float*)d_in[0];
    const float* v_in     = (const float*)d_in[1];
    const float* g_in     = (const float*)d_in[2];
    const float* b_in     = (const float*)d_in[3];
    const float* codebook = (const float*)d_in[4];
    const float* v_out    = (const float*)d_in[5];
    const float* g_out    = (const float*)d_in[6];
    const float* b_out    = (const float*)d_in[7];
    float* out            = (float*)d_out;
    float* ws             = (float*)d_ws;

    hipLaunchKernelGGL(k0_prep, dim3(29), dim3(256), 0, stream,
                       v_in, g_in, codebook, v_out, g_out, ws);
    hipLaunchKernelGGL(k_mega, dim3(512), dim3(256), 0, stream,
                       z, b_in, codebook, b_out, out, ws);
}